// Round 3
// baseline (87.314 us; speedup 1.0000x reference)
//
#include <hip/hip_runtime.h>
#include <math.h>

#define N_LAYERS 5
#define NG 20

// ---------------------------------------------------------------------------
// Pre-kernel: compose the 20 shared U3 gates + ring CNOTs into one 16x16
// complex unitary W, stored interleaved (re,im): W[(j*16+k)*2 + {0,1}]
// = <j| U |k>. One wave; thread k (k<16) propagates basis column e_k.
// ---------------------------------------------------------------------------
__global__ __launch_bounds__(64) void compose_W(const float* __restrict__ w,
                                                float* __restrict__ W) {
    __shared__ float g[NG][8];
    const int t = threadIdx.x;
    if (t < NG) {
        float th = w[t * 3 + 0], ph = w[t * 3 + 1], la = w[t * 3 + 2];
        float st, ct, sl, cl, sp, cp, spl, cpl;
        sincosf(th * 0.5f, &st, &ct);
        sincosf(la, &sl, &cl);
        sincosf(ph, &sp, &cp);
        sincosf(ph + la, &spl, &cpl);
        g[t][0] = ct;        g[t][1] = 0.0f;
        g[t][2] = -cl * st;  g[t][3] = -sl * st;
        g[t][4] = cp * st;   g[t][5] = sp * st;
        g[t][6] = cpl * ct;  g[t][7] = spl * ct;
    }
    __syncthreads();
    if (t >= 16) return;

    float ar[16], ai[16];
#pragma unroll
    for (int i = 0; i < 16; i++) { ar[i] = 0.0f; ai[i] = 0.0f; }
    ar[t] = 1.0f;

#pragma unroll
    for (int l = 0; l < N_LAYERS; l++) {
#pragma unroll
        for (int wi = 0; wi < 4; wi++) {
            const float* gm = g[l * 4 + wi];
            const float m00r = gm[0];
            const float m01r = gm[2], m01i = gm[3];
            const float m10r = gm[4], m10i = gm[5];
            const float m11r = gm[6], m11i = gm[7];
            const int stride = 8 >> wi;
#pragma unroll
            for (int base = 0; base < 16; base++) {
                if (base & stride) continue;
                const int i1 = base + stride;
                const float s0r = ar[base], s0i = ai[base];
                const float s1r = ar[i1],   s1i = ai[i1];
                ar[base] = m00r * s0r + m01r * s1r - m01i * s1i;
                ai[base] = m00r * s0i + m01r * s1i + m01i * s1r;
                ar[i1]   = m10r * s0r - m10i * s0i + m11r * s1r - m11i * s1i;
                ai[i1]   = m10r * s0i + m10i * s0r + m11r * s1i + m11i * s1r;
            }
        }
        const int ringc[4] = {0, 1, 2, 3};
        const int ringt[4] = {1, 2, 3, 0};
#pragma unroll
        for (int e = 0; e < 4; e++) {
            const int cm = 8 >> ringc[e];
            const int tm = 8 >> ringt[e];
#pragma unroll
            for (int idx = 0; idx < 16; idx++) {
                if ((idx & cm) && !(idx & tm)) {
                    const int j = idx | tm;
                    float tr = ar[idx]; ar[idx] = ar[j]; ar[j] = tr;
                    float ti = ai[idx]; ai[idx] = ai[j]; ai[j] = ti;
                }
            }
        }
    }
#pragma unroll
    for (int j = 0; j < 16; j++) {
        W[(j * 16 + t) * 2 + 0] = ar[j];
        W[(j * 16 + t) * 2 + 1] = ai[j];
    }
}

// ---------------------------------------------------------------------------
// Main kernel: W staged in LDS once per block (broadcast reads, no global
// traffic in the hot loop). Per sample: psi0 = tensor product of encoding
// columns (native sincos), psi = W*psi0 via ds_read_b128 + split-accumulator
// FMAs, probs, butterfly +/- reduction to <Z_i>.
// ---------------------------------------------------------------------------
__global__ __launch_bounds__(256) void qmain(const float* __restrict__ x,
                                             const float* __restrict__ Wg,
                                             float* __restrict__ out) {
    __shared__ float Ws[512];  // W interleaved (re,im), row-major: row j at Ws+32j
    const int t = threadIdx.x;
    if (t < 128) ((float4*)Ws)[t] = ((const float4*)Wg)[t];
    __syncthreads();

    const int b = blockIdx.x * 256 + t;
    const float4 xv = ((const float4*)x)[b];
    const float xs[4] = {xv.x, xv.y, xv.z, xv.w};

    // encoding columns: [cos(x/2), e^{ix} sin(x/2)]
    float vr[4][2], vi[4][2];
#pragma unroll
    for (int i = 0; i < 4; i++) {
        const float st = __sinf(xs[i] * 0.5f);
        const float ct = __cosf(xs[i] * 0.5f);
        const float sx = __sinf(xs[i]);
        const float cx = __cosf(xs[i]);
        vr[i][0] = ct;      vi[i][0] = 0.0f;
        vr[i][1] = cx * st; vi[i][1] = sx * st;
    }

    // tensor product -> 16 complex amps (wire0 = bit3)
    float w01r[4], w01i[4], w23r[4], w23i[4];
#pragma unroll
    for (int a = 0; a < 2; a++) {
#pragma unroll
        for (int c = 0; c < 2; c++) {
            w01r[a * 2 + c] = vr[0][a] * vr[1][c] - vi[0][a] * vi[1][c];
            w01i[a * 2 + c] = vr[0][a] * vi[1][c] + vi[0][a] * vr[1][c];
            w23r[a * 2 + c] = vr[2][a] * vr[3][c] - vi[2][a] * vi[3][c];
            w23i[a * 2 + c] = vr[2][a] * vi[3][c] + vi[2][a] * vr[3][c];
        }
    }
    float sr[16], si[16];
#pragma unroll
    for (int hi = 0; hi < 4; hi++) {
#pragma unroll
        for (int lo = 0; lo < 4; lo++) {
            sr[hi * 4 + lo] = w01r[hi] * w23r[lo] - w01i[hi] * w23i[lo];
            si[hi * 4 + lo] = w01r[hi] * w23i[lo] + w01i[hi] * w23r[lo];
        }
    }

    // psi = W * psi0 ; p_j = |psi_j|^2. Row reads are wave-uniform LDS
    // broadcasts (ds_read_b128, no bank conflicts). Two accumulator pairs
    // (even/odd k) halve the FMA dependency chain.
    float p[16];
#pragma unroll
    for (int j = 0; j < 16; j++) {
        const float4* row = (const float4*)(Ws + j * 32);
        float pr0 = 0.0f, pr1 = 0.0f, pi0 = 0.0f, pi1 = 0.0f;
#pragma unroll
        for (int kk = 0; kk < 8; kk++) {
            const float4 q = row[kk];  // (Wr[2kk], Wi[2kk], Wr[2kk+1], Wi[2kk+1])
            const int k = kk * 2;
            pr0 = fmaf(q.x, sr[k], pr0);
            pr0 = fmaf(-q.y, si[k], pr0);
            pi0 = fmaf(q.x, si[k], pi0);
            pi0 = fmaf(q.y, sr[k], pi0);
            pr1 = fmaf(q.z, sr[k + 1], pr1);
            pr1 = fmaf(-q.w, si[k + 1], pr1);
            pi1 = fmaf(q.z, si[k + 1], pi1);
            pi1 = fmaf(q.w, sr[k + 1], pi1);
        }
        const float prr = pr0 + pr1;
        const float pii = pi0 + pi1;
        p[j] = prr * prr + pii * pii;
    }

    // butterfly signed reduction: bit0=wire3 ... bit3=wire0
    const float a0 = p[0] + p[1],   a1 = p[2] + p[3],   a2 = p[4] + p[5],   a3 = p[6] + p[7];
    const float a4 = p[8] + p[9],   a5 = p[10] + p[11], a6 = p[12] + p[13], a7 = p[14] + p[15];
    const float z3 = (p[0] - p[1]) + (p[2] - p[3]) + (p[4] - p[5]) + (p[6] - p[7])
                   + (p[8] - p[9]) + (p[10] - p[11]) + (p[12] - p[13]) + (p[14] - p[15]);
    const float b0 = a0 + a1, b1 = a2 + a3, b2 = a4 + a5, b3 = a6 + a7;
    const float z2 = (a0 - a1) + (a2 - a3) + (a4 - a5) + (a6 - a7);
    const float c0 = b0 + b1, c1 = b2 + b3;
    const float z1 = (b0 - b1) + (b2 - b3);
    const float z0 = c0 - c1;

    ((float4*)out)[b] = make_float4(z0, z1, z2, z3);
}

extern "C" void kernel_launch(void* const* d_in, const int* in_sizes, int n_in,
                              void* d_out, int out_size, void* d_ws, size_t ws_size,
                              hipStream_t stream) {
    const float* x = (const float*)d_in[0];   // [B,4] fp32
    const float* w = (const float*)d_in[1];   // [5,4,3] fp32
    float* out = (float*)d_out;               // [B,4] fp32
    float* W = (float*)d_ws;                  // 16*16*2 floats = 2 KB
    const int b = in_sizes[0] / 4;

    compose_W<<<1, 64, 0, stream>>>(w, W);
    qmain<<<b / 256, 256, 0, stream>>>(x, W, out);
}

// Round 4
// 87.214 us; speedup vs baseline: 1.0011x; 1.0011x over previous
//
#include <hip/hip_runtime.h>
#include <math.h>

#define N_LAYERS 5
#define NG 20

typedef float sf16 __attribute__((ext_vector_type(16)));

// ---------------------------------------------------------------------------
// Pre-kernel: compose the 20 shared U3 gates + ring CNOTs into one 16x16
// complex unitary W, stored interleaved (re,im): W[(j*16+k)*2 + {0,1}]
// = <j| U |k>. One wave; thread k (k<16) propagates basis column e_k.
// ---------------------------------------------------------------------------
__global__ __launch_bounds__(64) void compose_W(const float* __restrict__ w,
                                                float* __restrict__ W) {
    __shared__ float g[NG][8];
    const int t = threadIdx.x;
    if (t < NG) {
        float th = w[t * 3 + 0], ph = w[t * 3 + 1], la = w[t * 3 + 2];
        float st, ct, sl, cl, sp, cp, spl, cpl;
        sincosf(th * 0.5f, &st, &ct);
        sincosf(la, &sl, &cl);
        sincosf(ph, &sp, &cp);
        sincosf(ph + la, &spl, &cpl);
        g[t][0] = ct;        g[t][1] = 0.0f;
        g[t][2] = -cl * st;  g[t][3] = -sl * st;
        g[t][4] = cp * st;   g[t][5] = sp * st;
        g[t][6] = cpl * ct;  g[t][7] = spl * ct;
    }
    __syncthreads();
    if (t >= 16) return;

    float ar[16], ai[16];
#pragma unroll
    for (int i = 0; i < 16; i++) { ar[i] = 0.0f; ai[i] = 0.0f; }
    ar[t] = 1.0f;

#pragma unroll
    for (int l = 0; l < N_LAYERS; l++) {
#pragma unroll
        for (int wi = 0; wi < 4; wi++) {
            const float* gm = g[l * 4 + wi];
            const float m00r = gm[0];
            const float m01r = gm[2], m01i = gm[3];
            const float m10r = gm[4], m10i = gm[5];
            const float m11r = gm[6], m11i = gm[7];
            const int stride = 8 >> wi;
#pragma unroll
            for (int base = 0; base < 16; base++) {
                if (base & stride) continue;
                const int i1 = base + stride;
                const float s0r = ar[base], s0i = ai[base];
                const float s1r = ar[i1],   s1i = ai[i1];
                ar[base] = m00r * s0r + m01r * s1r - m01i * s1i;
                ai[base] = m00r * s0i + m01r * s1i + m01i * s1r;
                ar[i1]   = m10r * s0r - m10i * s0i + m11r * s1r - m11i * s1i;
                ai[i1]   = m10r * s0i + m10i * s0r + m11r * s1i + m11i * s1r;
            }
        }
        const int ringc[4] = {0, 1, 2, 3};
        const int ringt[4] = {1, 2, 3, 0};
#pragma unroll
        for (int e = 0; e < 4; e++) {
            const int cm = 8 >> ringc[e];
            const int tm = 8 >> ringt[e];
#pragma unroll
            for (int idx = 0; idx < 16; idx++) {
                if ((idx & cm) && !(idx & tm)) {
                    const int j = idx | tm;
                    float tr = ar[idx]; ar[idx] = ar[j]; ar[j] = tr;
                    float ti = ai[idx]; ai[idx] = ai[j]; ai[j] = ti;
                }
            }
        }
    }
#pragma unroll
    for (int j = 0; j < 16; j++) {
        W[(j * 16 + t) * 2 + 0] = ar[j];
        W[(j * 16 + t) * 2 + 1] = ai[j];
    }
}

// ---------------------------------------------------------------------------
// Main kernel: W fetched row-by-row into SGPRs via inline-asm s_load_dwordx16
// (scalar K$ pipe — no VMEM, no LDS in the hot loop). The 1024-FMA complex
// matvec uses one SGPR operand per v_fma (legal: <=1 SGPR read per VALU op).
// ---------------------------------------------------------------------------
__global__ __launch_bounds__(256) void qmain(const float* __restrict__ x,
                                             const float* __restrict__ Wg,
                                             float* __restrict__ out) {
    const int b = blockIdx.x * 256 + threadIdx.x;
    const float4 xv = ((const float4*)x)[b];
    const float xs[4] = {xv.x, xv.y, xv.z, xv.w};

    // encoding columns: [cos(x/2), e^{ix} sin(x/2)]
    float vr[4][2], vi[4][2];
#pragma unroll
    for (int i = 0; i < 4; i++) {
        const float st = __sinf(xs[i] * 0.5f);
        const float ct = __cosf(xs[i] * 0.5f);
        const float sx = __sinf(xs[i]);
        const float cx = __cosf(xs[i]);
        vr[i][0] = ct;      vi[i][0] = 0.0f;
        vr[i][1] = cx * st; vi[i][1] = sx * st;
    }

    // tensor product -> 16 complex amps (wire0 = bit3)
    float w01r[4], w01i[4], w23r[4], w23i[4];
#pragma unroll
    for (int a = 0; a < 2; a++) {
#pragma unroll
        for (int c = 0; c < 2; c++) {
            w01r[a * 2 + c] = vr[0][a] * vr[1][c] - vi[0][a] * vi[1][c];
            w01i[a * 2 + c] = vr[0][a] * vi[1][c] + vi[0][a] * vr[1][c];
            w23r[a * 2 + c] = vr[2][a] * vr[3][c] - vi[2][a] * vi[3][c];
            w23i[a * 2 + c] = vr[2][a] * vi[3][c] + vi[2][a] * vr[3][c];
        }
    }
    float sr[16], si[16];
#pragma unroll
    for (int hi = 0; hi < 4; hi++) {
#pragma unroll
        for (int lo = 0; lo < 4; lo++) {
            sr[hi * 4 + lo] = w01r[hi] * w23r[lo] - w01i[hi] * w23i[lo];
            si[hi * 4 + lo] = w01r[hi] * w23i[lo] + w01i[hi] * w23r[lo];
        }
    }

    // psi = W * psi0 ; p_j = |psi_j|^2. Row j (32 floats) arrives in 32 SGPRs
    // via two s_load_dwordx16 (waitcnt inside the asm keeps uses safe).
    float p[16];
#pragma unroll
    for (int j = 0; j < 16; j++) {
        sf16 wa, wb;  // wa = (re,im) pairs k=0..7, wb = k=8..15
        asm volatile("s_load_dwordx16 %0, %2, %3\n\t"
                     "s_load_dwordx16 %1, %2, %4\n\t"
                     "s_waitcnt lgkmcnt(0)"
                     : "=&s"(wa), "=&s"(wb)
                     : "s"(Wg), "i"(j * 128), "i"(j * 128 + 64));
        float pr0 = 0.0f, pr1 = 0.0f, pi0 = 0.0f, pi1 = 0.0f;
#pragma unroll
        for (int k = 0; k < 8; k++) {
            const float wr0 = wa[2 * k], wi0 = wa[2 * k + 1];
            const float wr1 = wb[2 * k], wi1 = wb[2 * k + 1];
            pr0 = fmaf(wr0, sr[k], pr0);
            pr0 = fmaf(-wi0, si[k], pr0);
            pi0 = fmaf(wr0, si[k], pi0);
            pi0 = fmaf(wi0, sr[k], pi0);
            pr1 = fmaf(wr1, sr[k + 8], pr1);
            pr1 = fmaf(-wi1, si[k + 8], pr1);
            pi1 = fmaf(wr1, si[k + 8], pi1);
            pi1 = fmaf(wi1, sr[k + 8], pi1);
        }
        const float prr = pr0 + pr1;
        const float pii = pi0 + pi1;
        p[j] = prr * prr + pii * pii;
    }

    // butterfly signed reduction: bit0=wire3 ... bit3=wire0
    const float a0 = p[0] + p[1],   a1 = p[2] + p[3],   a2 = p[4] + p[5],   a3 = p[6] + p[7];
    const float a4 = p[8] + p[9],   a5 = p[10] + p[11], a6 = p[12] + p[13], a7 = p[14] + p[15];
    const float z3 = (p[0] - p[1]) + (p[2] - p[3]) + (p[4] - p[5]) + (p[6] - p[7])
                   + (p[8] - p[9]) + (p[10] - p[11]) + (p[12] - p[13]) + (p[14] - p[15]);
    const float b0 = a0 + a1, b1 = a2 + a3, b2 = a4 + a5, b3 = a6 + a7;
    const float z2 = (a0 - a1) + (a2 - a3) + (a4 - a5) + (a6 - a7);
    const float c0 = b0 + b1, c1 = b2 + b3;
    const float z1 = (b0 - b1) + (b2 - b3);
    const float z0 = c0 - c1;

    ((float4*)out)[b] = make_float4(z0, z1, z2, z3);
}

extern "C" void kernel_launch(void* const* d_in, const int* in_sizes, int n_in,
                              void* d_out, int out_size, void* d_ws, size_t ws_size,
                              hipStream_t stream) {
    const float* x = (const float*)d_in[0];   // [B,4] fp32
    const float* w = (const float*)d_in[1];   // [5,4,3] fp32
    float* out = (float*)d_out;               // [B,4] fp32
    float* W = (float*)d_ws;                  // 16*16*2 floats = 2 KB
    const int b = in_sizes[0] / 4;

    compose_W<<<1, 64, 0, stream>>>(w, W);
    qmain<<<b / 256, 256, 0, stream>>>(x, W, out);
}